// Round 2
// baseline (658.239 us; speedup 1.0000x reference)
//
#include <hip/hip_runtime.h>

#define DEVI __device__ __forceinline__

typedef __attribute__((ext_vector_type(8))) short bf16x8;
typedef __attribute__((ext_vector_type(4))) float f32x4;

static constexpr int NM = 20000, ND = 8000, NE = 200000;
static constexpr int FIN = 384, H = 512, H1 = 512, O = 256;

DEVI float bf2f(unsigned int u){ union{unsigned int i; float f;}v; v.i=u<<16; return v.f; }
DEVI unsigned int f2bf(float f){ union{float f; unsigned int i;}v; v.f=f;
  return (v.i + 0x7FFFu + ((v.i>>16)&1u))>>16; }

DEVI void gload16(const void* g, void* l){
  __builtin_amdgcn_global_load_lds((const __attribute__((address_space(1))) unsigned int*)g,
                                   (__attribute__((address_space(3))) unsigned int*)l, 16, 0, 0);
}

// ---------------- GEMM: C[M][N] = A[M][Ktot] @ W[Ktot][N] (+bias +emb / relu) ----------------
// A is split: k in [0,KA) from A0, [KA,Ktot) from A1 (each row-major, stride = its own K-width).
// WT is W transposed: [N][Ktot] bf16. EPI: 0=enc(+bias+emb, bf16 out), 1=l1(+bias,relu,bf16 out),
// 2=l2(+bias, f32 out).
template<int EPI>
__global__ __launch_bounds__(256)
void gemm_bf16(const unsigned short* __restrict__ A0,
               const unsigned short* __restrict__ A1, int KA,
               const unsigned short* __restrict__ WT, int Ktot,
               const float* __restrict__ bias,
               const float* __restrict__ emb, const int* __restrict__ ids,
               void* __restrict__ outp, int M, int N)
{
  __shared__ unsigned short sA[128*64];
  __shared__ unsigned short sB[128*64];
  const int tid  = threadIdx.x;
  const int lane = tid & 63;
  const int wv   = tid >> 6;
  const int wr   = wv >> 1, wc = wv & 1;
  const int bm0  = blockIdx.x * 128;
  const int bn0  = blockIdx.y * 128;

  f32x4 acc[4][4];
  #pragma unroll
  for (int m=0;m<4;++m)
    #pragma unroll
    for (int n=0;n<4;++n) acc[m][n] = (f32x4){0.f,0.f,0.f,0.f};

  const int r = tid >> 3;   // 0..31 (tile row within a 32-row stripe)
  const int c = tid & 7;    // 16B chunk within the 128B row
  const int KT = Ktot >> 6;

  for (int kt = 0; kt < KT; ++kt) {
    const int kbase = kt << 6;
    const unsigned short* Ap; int ka, astr;
    if (kbase < KA) { Ap = A0; ka = kbase;      astr = KA; }
    else            { Ap = A1; ka = kbase - KA; astr = Ktot - KA; }
    #pragma unroll
    for (int it = 0; it < 4; ++it) {
      const int row = r + it*32;
      int grA = bm0 + row; grA = grA < M ? grA : M-1;       // clamp tail rows
      const int cc = (c ^ (row & 7)) * 8;                   // pre-swizzled global source
      gload16(Ap + (size_t)grA*astr + ka + cc,    &sA[row*64 + c*8]);
      gload16(WT + (size_t)(bn0+row)*Ktot + kbase + cc, &sB[row*64 + c*8]);
    }
    __syncthreads();
    #pragma unroll
    for (int kk = 0; kk < 2; ++kk) {
      bf16x8 af[4], bfr[4];
      #pragma unroll
      for (int m=0;m<4;++m){
        const int rl = wr*64 + m*16 + (lane&15);
        const int ch = (kk*4 + (lane>>4)) ^ (rl&7);         // swizzled read
        af[m] = *(const bf16x8*)&sA[rl*64 + ch*8];
      }
      #pragma unroll
      for (int n=0;n<4;++n){
        const int rl = wc*64 + n*16 + (lane&15);
        const int ch = (kk*4 + (lane>>4)) ^ (rl&7);
        bfr[n] = *(const bf16x8*)&sB[rl*64 + ch*8];
      }
      #pragma unroll
      for (int m=0;m<4;++m)
        #pragma unroll
        for (int n=0;n<4;++n)
          acc[m][n] = __builtin_amdgcn_mfma_f32_16x16x32_bf16(af[m], bfr[n], acc[m][n], 0,0,0);
    }
    __syncthreads();
  }

  // epilogue: C/D layout col=lane&15, row=(lane>>4)*4+j  [verified m89/m91]
  const int cl = lane & 15;
  const int rg = lane >> 4;
  #pragma unroll
  for (int n=0;n<4;++n){
    const int col = bn0 + wc*64 + n*16 + cl;
    const float bv = bias[col];
    #pragma unroll
    for (int m=0;m<4;++m){
      const int rowb = bm0 + wr*64 + m*16 + rg*4;
      #pragma unroll
      for (int j=0;j<4;++j){
        const int row = rowb + j;
        if (row < M) {
          float v = acc[m][n][j] + bv;
          if constexpr (EPI==0) v += emb[(size_t)ids[row]*N + col];
          if constexpr (EPI==1) v = v > 0.f ? v : 0.f;
          if constexpr (EPI==2) ((float*)outp)[(size_t)row*N + col] = v;
          else ((unsigned short*)outp)[(size_t)row*N + col] = (unsigned short)f2bf(v);
        }
      }
    }
  }
}

// ---------------- mean aggregation: one wave per dst node, lane owns 8 channels ----------------
__global__ __launch_bounds__(256)
void agg_mean(const unsigned short* __restrict__ X,   // [Nsrc][512] bf16
              const int* __restrict__ off, const int* __restrict__ nbr,
              unsigned short* __restrict__ out, int Nd)
{
  const int node = blockIdx.x*4 + (threadIdx.x>>6);
  if (node >= Nd) return;
  const int lane = threadIdx.x & 63;
  const int s = off[node], e = off[node+1];
  float a[8] = {0.f,0.f,0.f,0.f,0.f,0.f,0.f,0.f};
  for (int j = s; j < e; ++j){
    const int src = nbr[j];
    const uint4 v = *(const uint4*)(X + (size_t)src*H + lane*8);
    a[0]+=bf2f(v.x&0xffffu); a[1]+=bf2f(v.x>>16);
    a[2]+=bf2f(v.y&0xffffu); a[3]+=bf2f(v.y>>16);
    a[4]+=bf2f(v.z&0xffffu); a[5]+=bf2f(v.z>>16);
    a[6]+=bf2f(v.w&0xffffu); a[7]+=bf2f(v.w>>16);
  }
  const float inv = (e > s) ? 1.0f/(float)(e - s) : 0.0f;
  uint4 o;
  o.x = f2bf(a[0]*inv) | (f2bf(a[1]*inv)<<16);
  o.y = f2bf(a[2]*inv) | (f2bf(a[3]*inv)<<16);
  o.z = f2bf(a[4]*inv) | (f2bf(a[5]*inv)<<16);
  o.w = f2bf(a[6]*inv) | (f2bf(a[7]*inv)<<16);
  *(uint4*)(out + (size_t)node*H + lane*8) = o;
}

// ---------------- weight transpose+convert (fp32 [K][N] -> bf16 [N][Ktot] with K-offset) -------
DEVI void tpart(int t, const float* __restrict__ in, unsigned short* __restrict__ out,
                int K, int N, int koff, int Kt)
{
  const int n = t / K, k = t - n*K;
  out[(size_t)n*Kt + koff + k] = (unsigned short)f2bf(in[(size_t)k*N + n]);
}

__global__ __launch_bounds__(256)
void prep_w(const float* Wm, const float* Wd,
            const float* W1mdl, const float* W1mdr, const float* W1dml, const float* W1dmr,
            const float* W2mdl, const float* W2mdr, const float* W2dml, const float* W2dmr,
            unsigned short* WmT, unsigned short* WdT,
            unsigned short* W1mdT, unsigned short* W1dmT,
            unsigned short* W2mdT, unsigned short* W2dmT)
{
  int t = blockIdx.x*256 + threadIdx.x;
  const int sE = FIN*H, s1 = H*H1, s2 = H1*O;
  if (t < sE){ tpart(t, Wm,    WmT,   FIN, H, 0,   FIN ); return; } t -= sE;
  if (t < sE){ tpart(t, Wd,    WdT,   FIN, H, 0,   FIN ); return; } t -= sE;
  if (t < s1){ tpart(t, W1mdl, W1mdT, H,  H1, 0,   1024); return; } t -= s1;
  if (t < s1){ tpart(t, W1mdr, W1mdT, H,  H1, 512, 1024); return; } t -= s1;
  if (t < s1){ tpart(t, W1dml, W1dmT, H,  H1, 0,   1024); return; } t -= s1;
  if (t < s1){ tpart(t, W1dmr, W1dmT, H,  H1, 512, 1024); return; } t -= s1;
  if (t < s2){ tpart(t, W2mdl, W2mdT, H1, O,  0,   1024); return; } t -= s2;
  if (t < s2){ tpart(t, W2mdr, W2mdT, H1, O,  512, 1024); return; } t -= s2;
  if (t < s2){ tpart(t, W2dml, W2dmT, H1, O,  0,   1024); return; } t -= s2;
  if (t < s2){ tpart(t, W2dmr, W2dmT, H1, O,  512, 1024); return; }
}

__global__ __launch_bounds__(256)
void cvt_feat(const float* __restrict__ fm, const float* __restrict__ fd,
              unsigned short* __restrict__ om, unsigned short* __restrict__ od)
{
  const long nm = (long)NM*FIN/4, nd = (long)ND*FIN/4;
  const long i = (long)blockIdx.x*256 + threadIdx.x;
  if (i >= nm+nd) return;
  const float4 v = (i < nm) ? ((const float4*)fm)[i] : ((const float4*)fd)[i-nm];
  uint2 o; o.x = f2bf(v.x) | (f2bf(v.y)<<16); o.y = f2bf(v.z) | (f2bf(v.w)<<16);
  if (i < nm) ((uint2*)om)[i] = o; else ((uint2*)od)[i-nm] = o;
}

// ---------------- CSR build ----------------
__global__ __launch_bounds__(256)
void hist_k(const int* __restrict__ esrc, const int* __restrict__ edst,
            int* __restrict__ degm, int* __restrict__ degd)
{
  const int e = blockIdx.x*256 + threadIdx.x;
  if (e < NE){ atomicAdd(&degd[edst[e]], 1); atomicAdd(&degm[esrc[e]], 1); }
}

__global__ __launch_bounds__(256)
void scan_k(const int* __restrict__ degd, int* __restrict__ offd, int* __restrict__ curd,
            const int* __restrict__ degm, int* __restrict__ offm, int* __restrict__ curm)
{
  const int* deg; int* off; int* cur; int n;
  if (blockIdx.x == 0){ deg=degd; off=offd; cur=curd; n=ND; }
  else                { deg=degm; off=offm; cur=curm; n=NM; }
  __shared__ int ps[257];
  const int t = threadIdx.x;
  const int chunk = (n + 255) >> 8;
  int lo = t*chunk;     if (lo > n) lo = n;
  int hi = lo + chunk;  if (hi > n) hi = n;
  int s = 0;
  for (int i=lo;i<hi;++i) s += deg[i];
  ps[t+1] = s;
  if (t==0) ps[0] = 0;
  __syncthreads();
  if (t==0){ for (int i=1;i<=256;++i) ps[i] += ps[i-1]; }
  __syncthreads();
  int run = ps[t];
  for (int i=lo;i<hi;++i){ off[i]=run; cur[i]=run; run += deg[i]; }
  if (t==0) off[n] = ps[256];
}

__global__ __launch_bounds__(256)
void fill_k(const int* __restrict__ esrc, const int* __restrict__ edst,
            int* __restrict__ curd, int* __restrict__ curm,
            int* __restrict__ ebd, int* __restrict__ ebs)
{
  const int e = blockIdx.x*256 + threadIdx.x;
  if (e < NE){
    const int s = esrc[e], d = edst[e];
    ebd[atomicAdd(&curd[d],1)] = s;   // src list grouped by dst
    ebs[atomicAdd(&curm[s],1)] = d;   // dst list grouped by src
  }
}

// ---------------- driver ----------------
extern "C" void kernel_launch(void* const* d_in, const int* in_sizes, int n_in,
                              void* d_out, int out_size, void* d_ws, size_t ws_size,
                              hipStream_t stream)
{
  (void)in_sizes; (void)n_in; (void)out_size; (void)ws_size;
  const float* mirna_feat=(const float*)d_in[0];
  const float* dis_feat  =(const float*)d_in[1];
  const int*   m_id =(const int*)d_in[2];
  const int*   d_id =(const int*)d_in[3];
  const int*   esrc =(const int*)d_in[4];
  const int*   edst =(const int*)d_in[5];
  const float* Wm=(const float*)d_in[6];  const float* bm=(const float*)d_in[7];
  const float* Wd=(const float*)d_in[8];  const float* bd=(const float*)d_in[9];
  const float* m_emb=(const float*)d_in[10]; const float* d_emb=(const float*)d_in[11];
  const float* W1mdl=(const float*)d_in[12]; const float* b1md=(const float*)d_in[13];
  const float* W1mdr=(const float*)d_in[14];
  const float* W1dml=(const float*)d_in[15]; const float* b1dm=(const float*)d_in[16];
  const float* W1dmr=(const float*)d_in[17];
  const float* W2mdl=(const float*)d_in[18]; const float* b2md=(const float*)d_in[19];
  const float* W2mdr=(const float*)d_in[20];
  const float* W2dml=(const float*)d_in[21]; const float* b2dm=(const float*)d_in[22];
  const float* W2dmr=(const float*)d_in[23];

  size_t off = 0;
  char* base = (char*)d_ws;
  auto alloc = [&](size_t bytes)->void*{
    off = (off + 255) & ~(size_t)255;
    void* p = base + off; off += bytes; return p;
  };
  unsigned short* featm = (unsigned short*)alloc((size_t)NM*FIN*2);
  unsigned short* featd = (unsigned short*)alloc((size_t)ND*FIN*2);
  unsigned short* WmT   = (unsigned short*)alloc((size_t)H*FIN*2);
  unsigned short* WdT   = (unsigned short*)alloc((size_t)H*FIN*2);
  unsigned short* W1mdT = (unsigned short*)alloc((size_t)H1*1024*2);
  unsigned short* W1dmT = (unsigned short*)alloc((size_t)H1*1024*2);
  unsigned short* W2mdT = (unsigned short*)alloc((size_t)O*1024*2);
  unsigned short* W2dmT = (unsigned short*)alloc((size_t)O*1024*2);
  unsigned short* xm    = (unsigned short*)alloc((size_t)NM*H*2);
  unsigned short* xd    = (unsigned short*)alloc((size_t)ND*H*2);
  unsigned short* aggm  = (unsigned short*)alloc((size_t)NM*H*2);
  unsigned short* aggd  = (unsigned short*)alloc((size_t)ND*H*2);
  unsigned short* hm    = (unsigned short*)alloc((size_t)NM*H1*2);
  unsigned short* hd    = (unsigned short*)alloc((size_t)ND*H1*2);
  int* degd = (int*)alloc((size_t)(ND+NM)*4);
  int* degm = degd + ND;
  int* offd = (int*)alloc((size_t)(ND+1)*4);
  int* offm = (int*)alloc((size_t)(NM+1)*4);
  int* curd = (int*)alloc((size_t)ND*4);
  int* curm = (int*)alloc((size_t)NM*4);
  int* ebd  = (int*)alloc((size_t)NE*4);
  int* ebs  = (int*)alloc((size_t)NE*4);

  hipMemsetAsync(degd, 0, (size_t)(ND+NM)*4, stream);
  prep_w<<<7680,256,0,stream>>>(Wm,Wd,W1mdl,W1mdr,W1dml,W1dmr,W2mdl,W2mdr,W2dml,W2dmr,
                                WmT,WdT,W1mdT,W1dmT,W2mdT,W2dmT);
  cvt_feat<<<10500,256,0,stream>>>(mirna_feat, dis_feat, featm, featd);
  hist_k<<<(NE+255)/256,256,0,stream>>>(esrc, edst, degm, degd);
  scan_k<<<2,256,0,stream>>>(degd, offd, curd, degm, offm, curm);
  fill_k<<<(NE+255)/256,256,0,stream>>>(esrc, edst, curd, curm, ebd, ebs);

  // encoders: x = feat@W + b + emb[id]
  gemm_bf16<0><<<dim3(157,4),256,0,stream>>>(featm, featm, FIN, WmT, FIN, bm, m_emb, m_id, xm, NM, H);
  gemm_bf16<0><<<dim3( 63,4),256,0,stream>>>(featd, featd, FIN, WdT, FIN, bd, d_emb, d_id, xd, ND, H);
  // layer-1 aggregation
  agg_mean<<<ND/4,256,0,stream>>>(xm, offd, ebd, aggd, ND);
  agg_mean<<<NM/4,256,0,stream>>>(xd, offm, ebs, aggm, NM);
  // layer-1 SAGE: h = relu(agg@Wl + x@Wr + b)
  gemm_bf16<1><<<dim3( 63,4),256,0,stream>>>(aggd, xd, H, W1mdT, 1024, b1md, nullptr, nullptr, hd, ND, H1);
  gemm_bf16<1><<<dim3(157,4),256,0,stream>>>(aggm, xm, H, W1dmT, 1024, b1dm, nullptr, nullptr, hm, NM, H1);
  // layer-2 aggregation (reuse agg buffers)
  agg_mean<<<ND/4,256,0,stream>>>(hm, offd, ebd, aggd, ND);
  agg_mean<<<NM/4,256,0,stream>>>(hd, offm, ebs, aggm, NM);
  // layer-2 SAGE: o = agg@Wl + h@Wr + b  (fp32, straight to d_out; order: o_m then o_d)
  float* out_m = (float*)d_out;
  float* out_d = out_m + (size_t)NM*O;
  gemm_bf16<2><<<dim3( 63,2),256,0,stream>>>(aggd, hd, H1, W2mdT, 1024, b2md, nullptr, nullptr, out_d, ND, O);
  gemm_bf16<2><<<dim3(157,2),256,0,stream>>>(aggm, hm, H1, W2dmT, 1024, b2dm, nullptr, nullptr, out_m, NM, O);
}

// Round 3
// 598.658 us; speedup vs baseline: 1.0995x; 1.0995x over previous
//
#include <hip/hip_runtime.h>

#define DEVI __device__ __forceinline__

typedef __attribute__((ext_vector_type(8))) short bf16x8;
typedef __attribute__((ext_vector_type(4))) float f32x4;

static constexpr int NM = 20000, ND = 8000, NE = 200000;
static constexpr int FIN = 384, H = 512, H1 = 512, O = 256;

DEVI float bf2f(unsigned int u){ union{unsigned int i; float f;}v; v.i=u<<16; return v.f; }
DEVI unsigned int f2bf(float f){ union{float f; unsigned int i;}v; v.f=f;
  return (v.i + 0x7FFFu + ((v.i>>16)&1u))>>16; }

DEVI void gload16(const void* g, void* l){
  __builtin_amdgcn_global_load_lds((const __attribute__((address_space(1))) unsigned int*)g,
                                   (__attribute__((address_space(3))) unsigned int*)l, 16, 0, 0);
}

// ---------------- merged-pair GEMM, 2-phase double-buffered ----------------
// C[M][N] = A[M][Ktot] @ W[Ktot][N] (+bias, +emb gather / relu / fp32-out)
// A split at KA between A0/A1 (row-major, own K-width). WT = W^T [N][Ktot] bf16.
// Two independent problems (m-part, d-part) share one grid; select by blockIdx.x.
struct GPart {
  const unsigned short* A0;
  const unsigned short* A1;
  const unsigned short* WT;
  const float* bias;
  const float* emb;
  const int* ids;
  void* out;
  int M;
  int nbx;
};

template<int EPI>   // 0=enc(+bias+emb,bf16) 1=l1(+bias,relu,bf16) 2=l2(+bias,fp32)
__global__ __launch_bounds__(256)
void gemm2(GPart P0, GPart P1, int KA, int Ktot, int N)
{
  __shared__ unsigned short sA[2][128*64];
  __shared__ unsigned short sB[2][128*64];

  int bx = blockIdx.x;
  const GPart& P = (bx < P0.nbx) ? P0 : P1;
  if (bx >= P0.nbx) bx -= P0.nbx;

  const int tid  = threadIdx.x;
  const int lane = tid & 63;
  const int wv   = tid >> 6;
  const int wr   = wv >> 1, wc = wv & 1;
  const int bm0  = bx * 128;
  const int bn0  = blockIdx.y * 128;
  const int M    = P.M;

  f32x4 acc[4][4];
  #pragma unroll
  for (int m=0;m<4;++m)
    #pragma unroll
    for (int n=0;n<4;++n) acc[m][n] = (f32x4){0.f,0.f,0.f,0.f};

  const int r = tid >> 3;   // 0..31: tile row within a 32-row stripe
  const int c = tid & 7;    // 16B chunk within the 128B row
  const int KT = Ktot >> 6;

  auto STAGE = [&](int buf, int kt){
    const int kbase = kt << 6;
    const unsigned short* Ap; int ka, astr;
    if (kbase < KA) { Ap = P.A0; ka = kbase;      astr = KA; }
    else            { Ap = P.A1; ka = kbase - KA; astr = Ktot - KA; }
    #pragma unroll
    for (int it = 0; it < 4; ++it) {
      const int row = r + it*32;
      int grA = bm0 + row; grA = grA < M ? grA : M-1;       // clamp tail rows
      const int cc = (c ^ (row & 7)) * 8;                   // pre-swizzled global source
      gload16(Ap   + (size_t)grA*astr      + ka    + cc, &sA[buf][row*64 + c*8]);
      gload16(P.WT + (size_t)(bn0+row)*Ktot + kbase + cc, &sB[buf][row*64 + c*8]);
    }
  };

  STAGE(0, 0);
  __syncthreads();                       // vmcnt(0) drain + barrier: tile0 ready
  int cur = 0;
  for (int kt = 0; kt < KT; ++kt) {
    if (kt + 1 < KT) STAGE(cur ^ 1, kt + 1);   // prefetch next tile (overlaps compute)
    #pragma unroll
    for (int kk = 0; kk < 2; ++kk) {
      bf16x8 af[4], bfr[4];
      #pragma unroll
      for (int m=0;m<4;++m){
        const int rl = wr*64 + m*16 + (lane&15);
        const int ch = (kk*4 + (lane>>4)) ^ (rl&7);         // swizzled read
        af[m] = *(const bf16x8*)&sA[cur][rl*64 + ch*8];
      }
      #pragma unroll
      for (int n=0;n<4;++n){
        const int rl = wc*64 + n*16 + (lane&15);
        const int ch = (kk*4 + (lane>>4)) ^ (rl&7);
        bfr[n] = *(const bf16x8*)&sB[cur][rl*64 + ch*8];
      }
      #pragma unroll
      for (int m=0;m<4;++m)
        #pragma unroll
        for (int n=0;n<4;++n)
          acc[m][n] = __builtin_amdgcn_mfma_f32_16x16x32_bf16(af[m], bfr[n], acc[m][n], 0,0,0);
    }
    __syncthreads();                     // drains prefetch vmcnt + syncs ds reads
    cur ^= 1;
  }

  // epilogue: C/D layout col=lane&15, row=(lane>>4)*4+j  [verified m89/m91]
  const int cl = lane & 15;
  const int rg = lane >> 4;
  #pragma unroll
  for (int n=0;n<4;++n){
    const int col = bn0 + wc*64 + n*16 + cl;
    const float bv = P.bias[col];
    #pragma unroll
    for (int m=0;m<4;++m){
      const int rowb = bm0 + wr*64 + m*16 + rg*4;
      #pragma unroll
      for (int j=0;j<4;++j){
        const int row = rowb + j;
        if (row < M) {
          float v = acc[m][n][j] + bv;
          if constexpr (EPI==0) v += P.emb[(size_t)P.ids[row]*N + col];
          if constexpr (EPI==1) v = v > 0.f ? v : 0.f;
          if constexpr (EPI==2) ((float*)P.out)[(size_t)row*N + col] = v;
          else ((unsigned short*)P.out)[(size_t)row*N + col] = (unsigned short)f2bf(v);
        }
      }
    }
  }
}

// ---------------- merged mean aggregation: both directions in one grid ----------------
// nodes [0,NM) -> aggm (gather Xd rows via offm/ebs); [NM,NM+ND) -> aggd (gather Xm via offd/ebd)
__global__ __launch_bounds__(256)
void agg2(const unsigned short* __restrict__ Xm, const unsigned short* __restrict__ Xd,
          const int* __restrict__ offm, const int* __restrict__ ebs,
          const int* __restrict__ offd, const int* __restrict__ ebd,
          unsigned short* __restrict__ aggm, unsigned short* __restrict__ aggd)
{
  int node = blockIdx.x*4 + (threadIdx.x>>6);
  const unsigned short* X; const int* off; const int* nbr; unsigned short* out;
  if (node < NM){ X = Xd; off = offm; nbr = ebs; out = aggm; }
  else          { node -= NM; X = Xm; off = offd; nbr = ebd; out = aggd; }
  const int lane = threadIdx.x & 63;
  const int s = off[node], e = off[node+1];
  float a[8] = {0.f,0.f,0.f,0.f,0.f,0.f,0.f,0.f};
  for (int j = s; j < e; ++j){
    const int src = nbr[j];
    const uint4 v = *(const uint4*)(X + (size_t)src*H + lane*8);
    a[0]+=bf2f(v.x&0xffffu); a[1]+=bf2f(v.x>>16);
    a[2]+=bf2f(v.y&0xffffu); a[3]+=bf2f(v.y>>16);
    a[4]+=bf2f(v.z&0xffffu); a[5]+=bf2f(v.z>>16);
    a[6]+=bf2f(v.w&0xffffu); a[7]+=bf2f(v.w>>16);
  }
  const float inv = (e > s) ? 1.0f/(float)(e - s) : 0.0f;
  uint4 o;
  o.x = f2bf(a[0]*inv) | (f2bf(a[1]*inv)<<16);
  o.y = f2bf(a[2]*inv) | (f2bf(a[3]*inv)<<16);
  o.z = f2bf(a[4]*inv) | (f2bf(a[5]*inv)<<16);
  o.w = f2bf(a[6]*inv) | (f2bf(a[7]*inv)<<16);
  *(uint4*)(out + (size_t)node*H + lane*8) = o;
}

// ---------------- merged prep: weight transpose+cvt, feature cvt, degree histogram ------
DEVI void tpart(int t, const float* __restrict__ in, unsigned short* __restrict__ out,
                int K, int N, int koff, int Kt)
{
  const int n = t / K, k = t - n*K;
  out[(size_t)n*Kt + koff + k] = (unsigned short)f2bf(in[(size_t)k*N + n]);
}

static constexpr int PREPW_BLOCKS = 7680;    // 1,966,080 weight elements / 256
static constexpr int CVT_BLOCKS   = 10500;   // 2,688,000 float4 groups / 256
static constexpr int HIST_BLOCKS  = (NE + 255)/256;

__global__ __launch_bounds__(256)
void prep_all(const float* Wm, const float* Wd,
              const float* W1mdl, const float* W1mdr, const float* W1dml, const float* W1dmr,
              const float* W2mdl, const float* W2mdr, const float* W2dml, const float* W2dmr,
              unsigned short* WmT, unsigned short* WdT,
              unsigned short* W1mdT, unsigned short* W1dmT,
              unsigned short* W2mdT, unsigned short* W2dmT,
              const float* fm, const float* fd, unsigned short* om, unsigned short* od,
              const int* esrc, const int* edst, int* degm, int* degd)
{
  const int b = blockIdx.x;
  if (b < PREPW_BLOCKS) {
    int t = b*256 + threadIdx.x;
    const int sE = FIN*H, s1 = H*H1, s2 = H1*O;
    if (t < sE){ tpart(t, Wm,    WmT,   FIN, H, 0,   FIN ); return; } t -= sE;
    if (t < sE){ tpart(t, Wd,    WdT,   FIN, H, 0,   FIN ); return; } t -= sE;
    if (t < s1){ tpart(t, W1mdl, W1mdT, H,  H1, 0,   1024); return; } t -= s1;
    if (t < s1){ tpart(t, W1mdr, W1mdT, H,  H1, 512, 1024); return; } t -= s1;
    if (t < s1){ tpart(t, W1dml, W1dmT, H,  H1, 0,   1024); return; } t -= s1;
    if (t < s1){ tpart(t, W1dmr, W1dmT, H,  H1, 512, 1024); return; } t -= s1;
    if (t < s2){ tpart(t, W2mdl, W2mdT, H1, O,  0,   1024); return; } t -= s2;
    if (t < s2){ tpart(t, W2mdr, W2mdT, H1, O,  512, 1024); return; } t -= s2;
    if (t < s2){ tpart(t, W2dml, W2dmT, H1, O,  0,   1024); return; } t -= s2;
    if (t < s2){ tpart(t, W2dmr, W2dmT, H1, O,  512, 1024); return; }
  } else if (b < PREPW_BLOCKS + CVT_BLOCKS) {
    const long nm = (long)NM*FIN/4, nd = (long)ND*FIN/4;
    const long i = (long)(b - PREPW_BLOCKS)*256 + threadIdx.x;
    if (i >= nm+nd) return;
    const float4 v = (i < nm) ? ((const float4*)fm)[i] : ((const float4*)fd)[i-nm];
    uint2 o; o.x = f2bf(v.x) | (f2bf(v.y)<<16); o.y = f2bf(v.z) | (f2bf(v.w)<<16);
    if (i < nm) ((uint2*)om)[i] = o; else ((uint2*)od)[i-nm] = o;
  } else {
    const int e = (b - PREPW_BLOCKS - CVT_BLOCKS)*256 + threadIdx.x;
    if (e < NE){ atomicAdd(&degd[edst[e]], 1); atomicAdd(&degm[esrc[e]], 1); }
  }
}

// ---------------- CSR scan + fill ----------------
__global__ __launch_bounds__(256)
void scan_k(const int* __restrict__ degd, int* __restrict__ offd, int* __restrict__ curd,
            const int* __restrict__ degm, int* __restrict__ offm, int* __restrict__ curm)
{
  const int* deg; int* off; int* cur; int n;
  if (blockIdx.x == 0){ deg=degd; off=offd; cur=curd; n=ND; }
  else                { deg=degm; off=offm; cur=curm; n=NM; }
  __shared__ int ps[257];
  const int t = threadIdx.x;
  const int chunk = (n + 255) >> 8;
  int lo = t*chunk;     if (lo > n) lo = n;
  int hi = lo + chunk;  if (hi > n) hi = n;
  int s = 0;
  for (int i=lo;i<hi;++i) s += deg[i];
  ps[t+1] = s;
  if (t==0) ps[0] = 0;
  __syncthreads();
  if (t==0){ for (int i=1;i<=256;++i) ps[i] += ps[i-1]; }
  __syncthreads();
  int run = ps[t];
  for (int i=lo;i<hi;++i){ off[i]=run; cur[i]=run; run += deg[i]; }
  if (t==0) off[n] = ps[256];
}

__global__ __launch_bounds__(256)
void fill_k(const int* __restrict__ esrc, const int* __restrict__ edst,
            int* __restrict__ curd, int* __restrict__ curm,
            int* __restrict__ ebd, int* __restrict__ ebs)
{
  const int e = blockIdx.x*256 + threadIdx.x;
  if (e < NE){
    const int s = esrc[e], d = edst[e];
    ebd[atomicAdd(&curd[d],1)] = s;   // src list grouped by dst
    ebs[atomicAdd(&curm[s],1)] = d;   // dst list grouped by src
  }
}

// ---------------- driver ----------------
extern "C" void kernel_launch(void* const* d_in, const int* in_sizes, int n_in,
                              void* d_out, int out_size, void* d_ws, size_t ws_size,
                              hipStream_t stream)
{
  (void)in_sizes; (void)n_in; (void)out_size; (void)ws_size;
  const float* mirna_feat=(const float*)d_in[0];
  const float* dis_feat  =(const float*)d_in[1];
  const int*   m_id =(const int*)d_in[2];
  const int*   d_id =(const int*)d_in[3];
  const int*   esrc =(const int*)d_in[4];
  const int*   edst =(const int*)d_in[5];
  const float* Wm=(const float*)d_in[6];  const float* bm=(const float*)d_in[7];
  const float* Wd=(const float*)d_in[8];  const float* bd=(const float*)d_in[9];
  const float* m_emb=(const float*)d_in[10]; const float* d_emb=(const float*)d_in[11];
  const float* W1mdl=(const float*)d_in[12]; const float* b1md=(const float*)d_in[13];
  const float* W1mdr=(const float*)d_in[14];
  const float* W1dml=(const float*)d_in[15]; const float* b1dm=(const float*)d_in[16];
  const float* W1dmr=(const float*)d_in[17];
  const float* W2mdl=(const float*)d_in[18]; const float* b2md=(const float*)d_in[19];
  const float* W2mdr=(const float*)d_in[20];
  const float* W2dml=(const float*)d_in[21]; const float* b2dm=(const float*)d_in[22];
  const float* W2dmr=(const float*)d_in[23];

  size_t off = 0;
  char* base = (char*)d_ws;
  auto alloc = [&](size_t bytes)->void*{
    off = (off + 255) & ~(size_t)255;
    void* p = base + off; off += bytes; return p;
  };
  unsigned short* featm = (unsigned short*)alloc((size_t)NM*FIN*2);
  unsigned short* featd = (unsigned short*)alloc((size_t)ND*FIN*2);
  unsigned short* WmT   = (unsigned short*)alloc((size_t)H*FIN*2);
  unsigned short* WdT   = (unsigned short*)alloc((size_t)H*FIN*2);
  unsigned short* W1mdT = (unsigned short*)alloc((size_t)H1*1024*2);
  unsigned short* W1dmT = (unsigned short*)alloc((size_t)H1*1024*2);
  unsigned short* W2mdT = (unsigned short*)alloc((size_t)O*1024*2);
  unsigned short* W2dmT = (unsigned short*)alloc((size_t)O*1024*2);
  unsigned short* xm    = (unsigned short*)alloc((size_t)NM*H*2);
  unsigned short* xd    = (unsigned short*)alloc((size_t)ND*H*2);
  unsigned short* aggm  = (unsigned short*)alloc((size_t)NM*H*2);
  unsigned short* aggd  = (unsigned short*)alloc((size_t)ND*H*2);
  unsigned short* hm    = (unsigned short*)alloc((size_t)NM*H1*2);
  unsigned short* hd    = (unsigned short*)alloc((size_t)ND*H1*2);
  int* degd = (int*)alloc((size_t)(ND+NM)*4);
  int* degm = degd + ND;
  int* offd = (int*)alloc((size_t)(ND+1)*4);
  int* offm = (int*)alloc((size_t)(NM+1)*4);
  int* curd = (int*)alloc((size_t)ND*4);
  int* curm = (int*)alloc((size_t)NM*4);
  int* ebd  = (int*)alloc((size_t)NE*4);
  int* ebs  = (int*)alloc((size_t)NE*4);

  hipMemsetAsync(degd, 0, (size_t)(ND+NM)*4, stream);
  prep_all<<<PREPW_BLOCKS + CVT_BLOCKS + HIST_BLOCKS, 256, 0, stream>>>(
      Wm,Wd,W1mdl,W1mdr,W1dml,W1dmr,W2mdl,W2mdr,W2dml,W2dmr,
      WmT,WdT,W1mdT,W1dmT,W2mdT,W2dmT,
      mirna_feat, dis_feat, featm, featd,
      esrc, edst, degm, degd);
  scan_k<<<2,256,0,stream>>>(degd, offd, curd, degm, offm, curm);
  fill_k<<<(NE+255)/256,256,0,stream>>>(esrc, edst, curd, curm, ebd, ebs);

  // encoders: x = feat@W + b + emb[id]   (m-part + d-part in one grid)
  {
    GPart p0{featm, featm, WmT, bm, m_emb, m_id, xm, NM, 157};
    GPart p1{featd, featd, WdT, bd, d_emb, d_id, xd, ND, 63};
    gemm2<0><<<dim3(220,4),256,0,stream>>>(p0, p1, FIN, FIN, H);
  }
  // layer-1 aggregation (both directions, one grid)
  agg2<<<(NM+ND)/4,256,0,stream>>>(xm, xd, offm, ebs, offd, ebd, aggm, aggd);
  // layer-1 SAGE: h = relu(agg@Wl + x@Wr + b)
  {
    GPart p0{aggm, xm, W1dmT, b1dm, nullptr, nullptr, hm, NM, 157};
    GPart p1{aggd, xd, W1mdT, b1md, nullptr, nullptr, hd, ND, 63};
    gemm2<1><<<dim3(220,4),256,0,stream>>>(p0, p1, H, 1024, H1);
  }
  // layer-2 aggregation (reuse agg buffers)
  agg2<<<(NM+ND)/4,256,0,stream>>>(hm, hd, offm, ebs, offd, ebd, aggm, aggd);
  // layer-2 SAGE: o = agg@Wl + h@Wr + b  (fp32, straight to d_out; order: o_m then o_d)
  float* out_m = (float*)d_out;
  float* out_d = out_m + (size_t)NM*O;
  {
    GPart p0{aggm, hm, W2dmT, b2dm, nullptr, nullptr, out_m, NM, 157};
    GPart p1{aggd, hd, W2mdT, b2md, nullptr, nullptr, out_d, ND, 63};
    gemm2<2><<<dim3(220,2),256,0,stream>>>(p0, p1, H1, 1024, O);
  }
}

// Round 4
// 542.849 us; speedup vs baseline: 1.2126x; 1.1028x over previous
//
#include <hip/hip_runtime.h>

#define DEVI __device__ __forceinline__

typedef __attribute__((ext_vector_type(8))) short bf16x8;
typedef __attribute__((ext_vector_type(4))) float f32x4;

static constexpr int NM = 20000, ND = 8000, NE = 200000;
static constexpr int FIN = 384, H = 512, H1 = 512, O = 256;

DEVI float bf2f(unsigned int u){ union{unsigned int i; float f;}v; v.i=u<<16; return v.f; }
DEVI unsigned int f2bf(float f){ union{float f; unsigned int i;}v; v.f=f;
  return (v.i + 0x7FFFu + ((v.i>>16)&1u))>>16; }

DEVI void gload16(const void* g, void* l){
  __builtin_amdgcn_global_load_lds((const __attribute__((address_space(1))) unsigned int*)g,
                                   (__attribute__((address_space(3))) unsigned int*)l, 16, 0, 0);
}

// ---------------- merged-pair GEMM, 8 waves/block, 2-phase double-buffered ----------------
// C[M][N] = A[M][Ktot] @ W[Ktot][N] (+bias, +emb gather / relu / fp32-out)
// A split at KA between A0/A1 (row-major, own K-width). WT = W^T [N][Ktot] bf16.
// Two independent problems (m-part, d-part) share one grid; select by blockIdx.x.
// Tile 128x128, BK=64, 512 threads = 8 waves in 4M x 2N; wave output = 32x64.
struct GPart {
  const unsigned short* A0;
  const unsigned short* A1;
  const unsigned short* WT;
  const float* bias;
  const float* emb;
  const int* ids;
  void* out;
  int M;
  int nbx;
};

template<int EPI>   // 0=enc(+bias+emb,bf16) 1=l1(+bias,relu,bf16) 2=l2(+bias,fp32)
__global__ __launch_bounds__(512, 4)
void gemm8w(GPart P0, GPart P1, int KA, int Ktot, int N)
{
  __shared__ unsigned short sA[2][128*64];
  __shared__ unsigned short sB[2][128*64];

  int bx = blockIdx.x;
  const bool snd = (bx >= P0.nbx);
  if (snd) bx -= P0.nbx;
  // per-field scalar selects (NO aggregate reference -> no scratch materialization)
  const unsigned short* A0  = snd ? P1.A0  : P0.A0;
  const unsigned short* A1  = snd ? P1.A1  : P0.A1;
  const unsigned short* WT  = snd ? P1.WT  : P0.WT;
  const float* bias         = snd ? P1.bias: P0.bias;
  const float* emb          = snd ? P1.emb : P0.emb;
  const int*   ids          = snd ? P1.ids : P0.ids;
  void*        outp         = snd ? P1.out : P0.out;
  const int    M            = snd ? P1.M   : P0.M;

  const int tid  = threadIdx.x;
  const int lane = tid & 63;
  const int wv   = tid >> 6;          // 0..7
  const int wr   = wv >> 1;           // 0..3 (M quadrant, 32 rows)
  const int wc   = wv & 1;            // 0..1 (N half, 64 cols)
  const int bm0  = bx * 128;
  const int bn0  = blockIdx.y * 128;

  f32x4 acc[2][4];
  #pragma unroll
  for (int m=0;m<2;++m)
    #pragma unroll
    for (int n=0;n<4;++n) acc[m][n] = (f32x4){0.f,0.f,0.f,0.f};

  const int r = tid >> 3;   // 0..63: tile row within a 64-row stripe
  const int c = tid & 7;    // 16B chunk within the 128B row
  const int KT = Ktot >> 6;

  auto STAGE = [&](int buf, int kt){
    const int kbase = kt << 6;
    const unsigned short* Ap; int ka, astr;
    if (kbase < KA) { Ap = A0; ka = kbase;      astr = KA; }
    else            { Ap = A1; ka = kbase - KA; astr = Ktot - KA; }
    #pragma unroll
    for (int it = 0; it < 2; ++it) {
      const int row = r + it*64;
      int grA = bm0 + row; grA = grA < M ? grA : M-1;       // clamp tail rows
      const int cc = (c ^ (row & 7)) * 8;                   // pre-swizzled global source
      gload16(Ap + (size_t)grA*astr       + ka    + cc, &sA[buf][row*64 + c*8]);
      gload16(WT + (size_t)(bn0+row)*Ktot + kbase + cc, &sB[buf][row*64 + c*8]);
    }
  };

  STAGE(0, 0);
  __syncthreads();                       // vmcnt(0) drain + barrier: tile0 ready
  int cur = 0;
  for (int kt = 0; kt < KT; ++kt) {
    if (kt + 1 < KT) STAGE(cur ^ 1, kt + 1);   // prefetch next tile (overlaps compute)
    #pragma unroll
    for (int kk = 0; kk < 2; ++kk) {
      bf16x8 af[2], bfr[4];
      #pragma unroll
      for (int m=0;m<2;++m){
        const int rl = wr*32 + m*16 + (lane&15);
        const int ch = (kk*4 + (lane>>4)) ^ (rl&7);         // swizzled read
        af[m] = *(const bf16x8*)&sA[cur][rl*64 + ch*8];
      }
      #pragma unroll
      for (int n=0;n<4;++n){
        const int rl = wc*64 + n*16 + (lane&15);
        const int ch = (kk*4 + (lane>>4)) ^ (rl&7);
        bfr[n] = *(const bf16x8*)&sB[cur][rl*64 + ch*8];
      }
      #pragma unroll
      for (int m=0;m<2;++m)
        #pragma unroll
        for (int n=0;n<4;++n)
          acc[m][n] = __builtin_amdgcn_mfma_f32_16x16x32_bf16(af[m], bfr[n], acc[m][n], 0,0,0);
    }
    __syncthreads();                     // drains prefetch vmcnt + syncs ds reads
    cur ^= 1;
  }

  // epilogue: C/D layout col=lane&15, row=(lane>>4)*4+j  [verified m89/m91]
  const int cl = lane & 15;
  const int rg = lane >> 4;
  #pragma unroll
  for (int n=0;n<4;++n){
    const int col = bn0 + wc*64 + n*16 + cl;
    const float bv = bias[col];
    #pragma unroll
    for (int m=0;m<2;++m){
      const int rowb = bm0 + wr*32 + m*16 + rg*4;
      #pragma unroll
      for (int j=0;j<4;++j){
        const int row = rowb + j;
        if (row < M) {
          float v = acc[m][n][j] + bv;
          if constexpr (EPI==0) v += emb[(size_t)ids[row]*N + col];
          if constexpr (EPI==1) v = v > 0.f ? v : 0.f;
          if constexpr (EPI==2) ((float*)outp)[(size_t)row*N + col] = v;
          else ((unsigned short*)outp)[(size_t)row*N + col] = (unsigned short)f2bf(v);
        }
      }
    }
  }
}

// ---------------- merged mean aggregation: both directions in one grid ----------------
// nodes [0,NM) -> aggm (gather Xd rows via offm/ebs); [NM,NM+ND) -> aggd (gather Xm via offd/ebd)
__global__ __launch_bounds__(256)
void agg2(const unsigned short* __restrict__ Xm, const unsigned short* __restrict__ Xd,
          const int* __restrict__ offm, const int* __restrict__ ebs,
          const int* __restrict__ offd, const int* __restrict__ ebd,
          unsigned short* __restrict__ aggm, unsigned short* __restrict__ aggd)
{
  int node = blockIdx.x*4 + (threadIdx.x>>6);
  const unsigned short* X; const int* off; const int* nbr; unsigned short* out;
  if (node < NM){ X = Xd; off = offm; nbr = ebs; out = aggm; }
  else          { node -= NM; X = Xm; off = offd; nbr = ebd; out = aggd; }
  const int lane = threadIdx.x & 63;
  const int s = off[node], e = off[node+1];
  float a[8] = {0.f,0.f,0.f,0.f,0.f,0.f,0.f,0.f};
  for (int j = s; j < e; ++j){
    const int src = nbr[j];
    const uint4 v = *(const uint4*)(X + (size_t)src*H + lane*8);
    a[0]+=bf2f(v.x&0xffffu); a[1]+=bf2f(v.x>>16);
    a[2]+=bf2f(v.y&0xffffu); a[3]+=bf2f(v.y>>16);
    a[4]+=bf2f(v.z&0xffffu); a[5]+=bf2f(v.z>>16);
    a[6]+=bf2f(v.w&0xffffu); a[7]+=bf2f(v.w>>16);
  }
  const float inv = (e > s) ? 1.0f/(float)(e - s) : 0.0f;
  uint4 o;
  o.x = f2bf(a[0]*inv) | (f2bf(a[1]*inv)<<16);
  o.y = f2bf(a[2]*inv) | (f2bf(a[3]*inv)<<16);
  o.z = f2bf(a[4]*inv) | (f2bf(a[5]*inv)<<16);
  o.w = f2bf(a[6]*inv) | (f2bf(a[7]*inv)<<16);
  *(uint4*)(out + (size_t)node*H + lane*8) = o;
}

// ---------------- merged prep: weight transpose+cvt, feature cvt, degree histogram ------
DEVI void tpart(int t, const float* __restrict__ in, unsigned short* __restrict__ out,
                int K, int N, int koff, int Kt)
{
  const int n = t / K, k = t - n*K;
  out[(size_t)n*Kt + koff + k] = (unsigned short)f2bf(in[(size_t)k*N + n]);
}

static constexpr int PREPW_BLOCKS = 7680;    // 1,966,080 weight elements / 256
static constexpr int CVT_BLOCKS   = 10500;   // 2,688,000 float4 groups / 256
static constexpr int HIST_BLOCKS  = (NE + 255)/256;

__global__ __launch_bounds__(256)
void prep_all(const float* Wm, const float* Wd,
              const float* W1mdl, const float* W1mdr, const float* W1dml, const float* W1dmr,
              const float* W2mdl, const float* W2mdr, const float* W2dml, const float* W2dmr,
              unsigned short* WmT, unsigned short* WdT,
              unsigned short* W1mdT, unsigned short* W1dmT,
              unsigned short* W2mdT, unsigned short* W2dmT,
              const float* fm, const float* fd, unsigned short* om, unsigned short* od,
              const int* esrc, const int* edst, int* degm, int* degd)
{
  const int b = blockIdx.x;
  if (b < PREPW_BLOCKS) {
    int t = b*256 + threadIdx.x;
    const int sE = FIN*H, s1 = H*H1, s2 = H1*O;
    if (t < sE){ tpart(t, Wm,    WmT,   FIN, H, 0,   FIN ); return; } t -= sE;
    if (t < sE){ tpart(t, Wd,    WdT,   FIN, H, 0,   FIN ); return; } t -= sE;
    if (t < s1){ tpart(t, W1mdl, W1mdT, H,  H1, 0,   1024); return; } t -= s1;
    if (t < s1){ tpart(t, W1mdr, W1mdT, H,  H1, 512, 1024); return; } t -= s1;
    if (t < s1){ tpart(t, W1dml, W1dmT, H,  H1, 0,   1024); return; } t -= s1;
    if (t < s1){ tpart(t, W1dmr, W1dmT, H,  H1, 512, 1024); return; } t -= s1;
    if (t < s2){ tpart(t, W2mdl, W2mdT, H1, O,  0,   1024); return; } t -= s2;
    if (t < s2){ tpart(t, W2mdr, W2mdT, H1, O,  512, 1024); return; } t -= s2;
    if (t < s2){ tpart(t, W2dml, W2dmT, H1, O,  0,   1024); return; } t -= s2;
    if (t < s2){ tpart(t, W2dmr, W2dmT, H1, O,  512, 1024); return; }
  } else if (b < PREPW_BLOCKS + CVT_BLOCKS) {
    const long nm = (long)NM*FIN/4, nd = (long)ND*FIN/4;
    const long i = (long)(b - PREPW_BLOCKS)*256 + threadIdx.x;
    if (i >= nm+nd) return;
    const float4 v = (i < nm) ? ((const float4*)fm)[i] : ((const float4*)fd)[i-nm];
    uint2 o; o.x = f2bf(v.x) | (f2bf(v.y)<<16); o.y = f2bf(v.z) | (f2bf(v.w)<<16);
    if (i < nm) ((uint2*)om)[i] = o; else ((uint2*)od)[i-nm] = o;
  } else {
    const int e = (b - PREPW_BLOCKS - CVT_BLOCKS)*256 + threadIdx.x;
    if (e < NE){ atomicAdd(&degd[edst[e]], 1); atomicAdd(&degm[esrc[e]], 1); }
  }
}

// ---------------- CSR scan + fill ----------------
__global__ __launch_bounds__(256)
void scan_k(const int* __restrict__ degd, int* __restrict__ offd, int* __restrict__ curd,
            const int* __restrict__ degm, int* __restrict__ offm, int* __restrict__ curm)
{
  const int* deg; int* off; int* cur; int n;
  if (blockIdx.x == 0){ deg=degd; off=offd; cur=curd; n=ND; }
  else                { deg=degm; off=offm; cur=curm; n=NM; }
  __shared__ int ps[257];
  const int t = threadIdx.x;
  const int chunk = (n + 255) >> 8;
  int lo = t*chunk;     if (lo > n) lo = n;
  int hi = lo + chunk;  if (hi > n) hi = n;
  int s = 0;
  for (int i=lo;i<hi;++i) s += deg[i];
  ps[t+1] = s;
  if (t==0) ps[0] = 0;
  __syncthreads();
  if (t==0){ for (int i=1;i<=256;++i) ps[i] += ps[i-1]; }
  __syncthreads();
  int run = ps[t];
  for (int i=lo;i<hi;++i){ off[i]=run; cur[i]=run; run += deg[i]; }
  if (t==0) off[n] = ps[256];
}

__global__ __launch_bounds__(256)
void fill_k(const int* __restrict__ esrc, const int* __restrict__ edst,
            int* __restrict__ curd, int* __restrict__ curm,
            int* __restrict__ ebd, int* __restrict__ ebs)
{
  const int e = blockIdx.x*256 + threadIdx.x;
  if (e < NE){
    const int s = esrc[e], d = edst[e];
    ebd[atomicAdd(&curd[d],1)] = s;   // src list grouped by dst
    ebs[atomicAdd(&curm[s],1)] = d;   // dst list grouped by src
  }
}

// ---------------- driver ----------------
extern "C" void kernel_launch(void* const* d_in, const int* in_sizes, int n_in,
                              void* d_out, int out_size, void* d_ws, size_t ws_size,
                              hipStream_t stream)
{
  (void)in_sizes; (void)n_in; (void)out_size; (void)ws_size;
  const float* mirna_feat=(const float*)d_in[0];
  const float* dis_feat  =(const float*)d_in[1];
  const int*   m_id =(const int*)d_in[2];
  const int*   d_id =(const int*)d_in[3];
  const int*   esrc =(const int*)d_in[4];
  const int*   edst =(const int*)d_in[5];
  const float* Wm=(const float*)d_in[6];  const float* bm=(const float*)d_in[7];
  const float* Wd=(const float*)d_in[8];  const float* bd=(const float*)d_in[9];
  const float* m_emb=(const float*)d_in[10]; const float* d_emb=(const float*)d_in[11];
  const float* W1mdl=(const float*)d_in[12]; const float* b1md=(const float*)d_in[13];
  const float* W1mdr=(const float*)d_in[14];
  const float* W1dml=(const float*)d_in[15]; const float* b1dm=(const float*)d_in[16];
  const float* W1dmr=(const float*)d_in[17];
  const float* W2mdl=(const float*)d_in[18]; const float* b2md=(const float*)d_in[19];
  const float* W2mdr=(const float*)d_in[20];
  const float* W2dml=(const float*)d_in[21]; const float* b2dm=(const float*)d_in[22];
  const float* W2dmr=(const float*)d_in[23];

  size_t off = 0;
  char* base = (char*)d_ws;
  auto alloc = [&](size_t bytes)->void*{
    off = (off + 255) & ~(size_t)255;
    void* p = base + off; off += bytes; return p;
  };
  unsigned short* featm = (unsigned short*)alloc((size_t)NM*FIN*2);
  unsigned short* featd = (unsigned short*)alloc((size_t)ND*FIN*2);
  unsigned short* WmT   = (unsigned short*)alloc((size_t)H*FIN*2);
  unsigned short* WdT   = (unsigned short*)alloc((size_t)H*FIN*2);
  unsigned short* W1mdT = (unsigned short*)alloc((size_t)H1*1024*2);
  unsigned short* W1dmT = (unsigned short*)alloc((size_t)H1*1024*2);
  unsigned short* W2mdT = (unsigned short*)alloc((size_t)O*1024*2);
  unsigned short* W2dmT = (unsigned short*)alloc((size_t)O*1024*2);
  unsigned short* xm    = (unsigned short*)alloc((size_t)NM*H*2);
  unsigned short* xd    = (unsigned short*)alloc((size_t)ND*H*2);
  unsigned short* aggm  = (unsigned short*)alloc((size_t)NM*H*2);
  unsigned short* aggd  = (unsigned short*)alloc((size_t)ND*H*2);
  unsigned short* hm    = (unsigned short*)alloc((size_t)NM*H1*2);
  unsigned short* hd    = (unsigned short*)alloc((size_t)ND*H1*2);
  int* degd = (int*)alloc((size_t)(ND+NM)*4);
  int* degm = degd + ND;
  int* offd = (int*)alloc((size_t)(ND+1)*4);
  int* offm = (int*)alloc((size_t)(NM+1)*4);
  int* curd = (int*)alloc((size_t)ND*4);
  int* curm = (int*)alloc((size_t)NM*4);
  int* ebd  = (int*)alloc((size_t)NE*4);
  int* ebs  = (int*)alloc((size_t)NE*4);

  hipMemsetAsync(degd, 0, (size_t)(ND+NM)*4, stream);
  prep_all<<<PREPW_BLOCKS + CVT_BLOCKS + HIST_BLOCKS, 256, 0, stream>>>(
      Wm,Wd,W1mdl,W1mdr,W1dml,W1dmr,W2mdl,W2mdr,W2dml,W2dmr,
      WmT,WdT,W1mdT,W1dmT,W2mdT,W2dmT,
      mirna_feat, dis_feat, featm, featd,
      esrc, edst, degm, degd);
  scan_k<<<2,256,0,stream>>>(degd, offd, curd, degm, offm, curm);
  fill_k<<<(NE+255)/256,256,0,stream>>>(esrc, edst, curd, curm, ebd, ebs);

  // encoders: x = feat@W + b + emb[id]   (m-part + d-part in one grid)
  {
    GPart p0{featm, featm, WmT, bm, m_emb, m_id, xm, NM, 157};
    GPart p1{featd, featd, WdT, bd, d_emb, d_id, xd, ND, 63};
    gemm8w<0><<<dim3(220,4),512,0,stream>>>(p0, p1, FIN, FIN, H);
  }
  // layer-1 aggregation (both directions, one grid)
  agg2<<<(NM+ND)/4,256,0,stream>>>(xm, xd, offm, ebs, offd, ebd, aggm, aggd);
  // layer-1 SAGE: h = relu(agg@Wl + x@Wr + b)
  {
    GPart p0{aggm, xm, W1dmT, b1dm, nullptr, nullptr, hm, NM, 157};
    GPart p1{aggd, xd, W1mdT, b1md, nullptr, nullptr, hd, ND, 63};
    gemm8w<1><<<dim3(220,4),512,0,stream>>>(p0, p1, H, 1024, H1);
  }
  // layer-2 aggregation (reuse agg buffers)
  agg2<<<(NM+ND)/4,256,0,stream>>>(hm, hd, offm, ebs, offd, ebd, aggm, aggd);
  // layer-2 SAGE: o = agg@Wl + h@Wr + b  (fp32, straight to d_out; order: o_m then o_d)
  float* out_m = (float*)d_out;
  float* out_d = out_m + (size_t)NM*O;
  {
    GPart p0{aggm, hm, W2dmT, b2dm, nullptr, nullptr, out_m, NM, 157};
    GPart p1{aggd, hd, W2mdT, b2md, nullptr, nullptr, out_d, ND, 63};
    gemm8w<2><<<dim3(220,2),512,0,stream>>>(p0, p1, H1, 1024, O);
  }
}

// Round 7
// 527.531 us; speedup vs baseline: 1.2478x; 1.0290x over previous
//
#include <hip/hip_runtime.h>

#define DEVI __device__ __forceinline__

typedef __attribute__((ext_vector_type(8))) short bf16x8;
typedef __attribute__((ext_vector_type(4))) float f32x4;

static constexpr int NM = 20000, ND = 8000, NE = 200000;
static constexpr int FIN = 384, H = 512, H1 = 512, O = 256;

DEVI float bf2f(unsigned int u){ union{unsigned int i; float f;}v; v.i=u<<16; return v.f; }
DEVI unsigned int f2bf(float f){ union{float f; unsigned int i;}v; v.f=f;
  return (v.i + 0x7FFFu + ((v.i>>16)&1u))>>16; }

DEVI void gload16(const void* g, void* l){
  __builtin_amdgcn_global_load_lds((const __attribute__((address_space(1))) unsigned int*)g,
                                   (__attribute__((address_space(3))) unsigned int*)l, 16, 0, 0);
}

// ---------------- merged-pair GEMM, 8 waves/block, BK=32, double-buffered ----------------
// C[M][N] = A[M][Ktot] @ W[Ktot][N] (+bias, +emb gather / relu / fp32-out)
// A split at KA between A0/A1 (row-major, own K-width). WT = W^T [N][Ktot] bf16.
// Tile 128x128, BK=32 (64B rows), 512 threads = 8 waves in 4M x 2N; wave output 32x64.
// LDS = 2buf x (128x32 A + 128x32 B) x 2B = 32 KB -> 4 blocks/CU (wave-capped), 100% occ.
// Swizzle: 16B chunk c of row r stored at c, sourced from global chunk c^((r>>1)&3);
// reads XOR the same mask -> conflict-free fragment reads (both-sides involution).
struct GPart {
  const unsigned short* A0;
  const unsigned short* A1;
  const unsigned short* WT;
  const float* bias;
  const float* emb;
  const int* ids;
  void* out;
  int M;
  int nbx;
};

template<int EPI>   // 0=enc(+bias+emb,bf16) 1=l1(+bias,relu,bf16) 2=l2(+bias,fp32)
__global__ __launch_bounds__(512, 8)
void gemm8w(GPart P0, GPart P1, int KA, int Ktot, int N)
{
  __shared__ unsigned short sA[2][128*32];
  __shared__ unsigned short sB[2][128*32];

  int bx = blockIdx.x;
  const bool snd = (bx >= P0.nbx);
  if (snd) bx -= P0.nbx;
  // per-field scalar selects (NO aggregate reference -> no scratch materialization)
  const unsigned short* A0  = snd ? P1.A0  : P0.A0;
  const unsigned short* A1  = snd ? P1.A1  : P0.A1;
  const unsigned short* WT  = snd ? P1.WT  : P0.WT;
  const float* bias         = snd ? P1.bias: P0.bias;
  const float* emb          = snd ? P1.emb : P0.emb;
  const int*   ids          = snd ? P1.ids : P0.ids;
  void*        outp         = snd ? P1.out : P0.out;
  const int    M            = snd ? P1.M   : P0.M;

  const int tid  = threadIdx.x;
  const int lane = tid & 63;
  const int wv   = tid >> 6;          // 0..7
  const int wr   = wv >> 1;           // 0..3 (M quadrant, 32 rows)
  const int wc   = wv & 1;            // 0..1 (N half, 64 cols)
  const int bm0  = bx * 128;
  const int bn0  = blockIdx.y * 128;

  f32x4 acc[2][4];
  #pragma unroll
  for (int m=0;m<2;++m)
    #pragma unroll
    for (int n=0;n<4;++n) acc[m][n] = (f32x4){0.f,0.f,0.f,0.f};

  const int r = tid >> 2;   // 0..127: tile row
  const int c = tid & 3;    // 16B chunk within the 64B row
  const int KT = Ktot >> 5;

  auto STAGE = [&](int buf, int kt){
    const int kbase = kt << 5;
    const unsigned short* Ap; int ka, astr;
    if (kbase < KA) { Ap = A0; ka = kbase;      astr = KA; }
    else            { Ap = A1; ka = kbase - KA; astr = Ktot - KA; }
    int grA = bm0 + r; grA = grA < M ? grA : M-1;         // clamp tail rows
    const int cc = (c ^ ((r>>1) & 3)) * 8;                // pre-swizzled global source
    gload16(Ap + (size_t)grA*astr       + ka    + cc, &sA[buf][r*32 + c*8]);
    gload16(WT + (size_t)(bn0+r)*Ktot   + kbase + cc, &sB[buf][r*32 + c*8]);
  };

  STAGE(0, 0);
  __syncthreads();                       // vmcnt(0) drain + barrier: tile0 ready
  int cur = 0;
  for (int kt = 0; kt < KT; ++kt) {
    if (kt + 1 < KT) STAGE(cur ^ 1, kt + 1);   // prefetch next tile (overlaps compute)
    bf16x8 af[2], bfr[4];
    #pragma unroll
    for (int m=0;m<2;++m){
      const int rl = wr*32 + m*16 + (lane&15);
      const int ch = (lane>>4) ^ ((rl>>1) & 3);           // swizzled read
      af[m] = *(const bf16x8*)&sA[cur][rl*32 + ch*8];
    }
    #pragma unroll
    for (int n=0;n<4;++n){
      const int rl = wc*64 + n*16 + (lane&15);
      const int ch = (lane>>4) ^ ((rl>>1) & 3);
      bfr[n] = *(const bf16x8*)&sB[cur][rl*32 + ch*8];
    }
    #pragma unroll
    for (int m=0;m<2;++m)
      #pragma unroll
      for (int n=0;n<4;++n)
        acc[m][n] = __builtin_amdgcn_mfma_f32_16x16x32_bf16(af[m], bfr[n], acc[m][n], 0,0,0);
    __syncthreads();                     // drains prefetch vmcnt + syncs ds reads
    cur ^= 1;
  }

  // epilogue: C/D layout col=lane&15, row=(lane>>4)*4+j  [verified m89/m91]
  const int cl = lane & 15;
  const int rg = lane >> 4;
  #pragma unroll
  for (int n=0;n<4;++n){
    const int col = bn0 + wc*64 + n*16 + cl;
    const float bv = bias[col];
    #pragma unroll
    for (int m=0;m<2;++m){
      const int rowb = bm0 + wr*32 + m*16 + rg*4;
      #pragma unroll
      for (int j=0;j<4;++j){
        const int row = rowb + j;
        if (row < M) {
          float v = acc[m][n][j] + bv;
          if constexpr (EPI==0) v += emb[(size_t)ids[row]*N + col];
          if constexpr (EPI==1) v = v > 0.f ? v : 0.f;
          if constexpr (EPI==2) ((float*)outp)[(size_t)row*N + col] = v;
          else ((unsigned short*)outp)[(size_t)row*N + col] = (unsigned short)f2bf(v);
        }
      }
    }
  }
}

// ---------------- merged mean aggregation: both directions in one grid ----------------
// nodes [0,NM) -> aggm (gather Xd rows via offm/ebs); [NM,NM+ND) -> aggd (gather Xm via offd/ebd)
__global__ __launch_bounds__(256)
void agg2(const unsigned short* __restrict__ Xm, const unsigned short* __restrict__ Xd,
          const int* __restrict__ offm, const int* __restrict__ ebs,
          const int* __restrict__ offd, const int* __restrict__ ebd,
          unsigned short* __restrict__ aggm, unsigned short* __restrict__ aggd)
{
  int node = blockIdx.x*4 + (threadIdx.x>>6);
  const unsigned short* X; const int* off; const int* nbr; unsigned short* out;
  if (node < NM){ X = Xd; off = offm; nbr = ebs; out = aggm; }
  else          { node -= NM; X = Xm; off = offd; nbr = ebd; out = aggd; }
  const int lane = threadIdx.x & 63;
  const int s = off[node], e = off[node+1];
  float a[8] = {0.f,0.f,0.f,0.f,0.f,0.f,0.f,0.f};
  for (int j = s; j < e; ++j){
    const int src = nbr[j];
    const uint4 v = *(const uint4*)(X + (size_t)src*H + lane*8);
    a[0]+=bf2f(v.x&0xffffu); a[1]+=bf2f(v.x>>16);
    a[2]+=bf2f(v.y&0xffffu); a[3]+=bf2f(v.y>>16);
    a[4]+=bf2f(v.z&0xffffu); a[5]+=bf2f(v.z>>16);
    a[6]+=bf2f(v.w&0xffffu); a[7]+=bf2f(v.w>>16);
  }
  const float inv = (e > s) ? 1.0f/(float)(e - s) : 0.0f;
  uint4 o;
  o.x = f2bf(a[0]*inv) | (f2bf(a[1]*inv)<<16);
  o.y = f2bf(a[2]*inv) | (f2bf(a[3]*inv)<<16);
  o.z = f2bf(a[4]*inv) | (f2bf(a[5]*inv)<<16);
  o.w = f2bf(a[6]*inv) | (f2bf(a[7]*inv)<<16);
  *(uint4*)(out + (size_t)node*H + lane*8) = o;
}

// ---------------- merged prep: weight transpose+cvt, feature cvt, degree histogram ------
DEVI void tpart(int t, const float* __restrict__ in, unsigned short* __restrict__ out,
                int K, int N, int koff, int Kt)
{
  const int n = t / K, k = t - n*K;
  out[(size_t)n*Kt + koff + k] = (unsigned short)f2bf(in[(size_t)k*N + n]);
}

static constexpr int PREPW_BLOCKS = 7680;    // 1,966,080 weight elements / 256
static constexpr int CVT_BLOCKS   = 10500;   // 2,688,000 float4 groups / 256
static constexpr int HIST_BLOCKS  = (NE + 255)/256;

__global__ __launch_bounds__(256)
void prep_all(const float* Wm, const float* Wd,
              const float* W1mdl, const float* W1mdr, const float* W1dml, const float* W1dmr,
              const float* W2mdl, const float* W2mdr, const float* W2dml, const float* W2dmr,
              unsigned short* WmT, unsigned short* WdT,
              unsigned short* W1mdT, unsigned short* W1dmT,
              unsigned short* W2mdT, unsigned short* W2dmT,
              const float* fm, const float* fd, unsigned short* om, unsigned short* od,
              const int* esrc, const int* edst, int* degm, int* degd)
{
  const int b = blockIdx.x;
  if (b < PREPW_BLOCKS) {
    int t = b*256 + threadIdx.x;
    const int sE = FIN*H, s1 = H*H1, s2 = H1*O;
    if (t < sE){ tpart(t, Wm,    WmT,   FIN, H, 0,   FIN ); return; } t -= sE;
    if (t < sE){ tpart(t, Wd,    WdT,   FIN, H, 0,   FIN ); return; } t -= sE;
    if (t < s1){ tpart(t, W1mdl, W1mdT, H,  H1, 0,   1024); return; } t -= s1;
    if (t < s1){ tpart(t, W1mdr, W1mdT, H,  H1, 512, 1024); return; } t -= s1;
    if (t < s1){ tpart(t, W1dml, W1dmT, H,  H1, 0,   1024); return; } t -= s1;
    if (t < s1){ tpart(t, W1dmr, W1dmT, H,  H1, 512, 1024); return; } t -= s1;
    if (t < s2){ tpart(t, W2mdl, W2mdT, H1, O,  0,   1024); return; } t -= s2;
    if (t < s2){ tpart(t, W2mdr, W2mdT, H1, O,  512, 1024); return; } t -= s2;
    if (t < s2){ tpart(t, W2dml, W2dmT, H1, O,  0,   1024); return; } t -= s2;
    if (t < s2){ tpart(t, W2dmr, W2dmT, H1, O,  512, 1024); return; }
  } else if (b < PREPW_BLOCKS + CVT_BLOCKS) {
    const long nm = (long)NM*FIN/4, nd = (long)ND*FIN/4;
    const long i = (long)(b - PREPW_BLOCKS)*256 + threadIdx.x;
    if (i >= nm+nd) return;
    const float4 v = (i < nm) ? ((const float4*)fm)[i] : ((const float4*)fd)[i-nm];
    uint2 o; o.x = f2bf(v.x) | (f2bf(v.y)<<16); o.y = f2bf(v.z) | (f2bf(v.w)<<16);
    if (i < nm) ((uint2*)om)[i] = o; else ((uint2*)od)[i-nm] = o;
  } else {
    const int e = (b - PREPW_BLOCKS - CVT_BLOCKS)*256 + threadIdx.x;
    if (e < NE){ atomicAdd(&degd[edst[e]], 1); atomicAdd(&degm[esrc[e]], 1); }
  }
}

// ---------------- CSR scan + fill ----------------
__global__ __launch_bounds__(256)
void scan_k(const int* __restrict__ degd, int* __restrict__ offd, int* __restrict__ curd,
            const int* __restrict__ degm, int* __restrict__ offm, int* __restrict__ curm)
{
  const int* deg; int* off; int* cur; int n;
  if (blockIdx.x == 0){ deg=degd; off=offd; cur=curd; n=ND; }
  else                { deg=degm; off=offm; cur=curm; n=NM; }
  __shared__ int ps[257];
  const int t = threadIdx.x;
  const int chunk = (n + 255) >> 8;
  int lo = t*chunk;     if (lo > n) lo = n;
  int hi = lo + chunk;  if (hi > n) hi = n;
  int s = 0;
  for (int i=lo;i<hi;++i) s += deg[i];
  ps[t+1] = s;
  if (t==0) ps[0] = 0;
  __syncthreads();
  if (t==0){ for (int i=1;i<=256;++i) ps[i] += ps[i-1]; }
  __syncthreads();
  int run = ps[t];
  for (int i=lo;i<hi;++i){ off[i]=run; cur[i]=run; run += deg[i]; }
  if (t==0) off[n] = ps[256];
}

__global__ __launch_bounds__(256)
void fill_k(const int* __restrict__ esrc, const int* __restrict__ edst,
            int* __restrict__ curd, int* __restrict__ curm,
            int* __restrict__ ebd, int* __restrict__ ebs)
{
  const int e = blockIdx.x*256 + threadIdx.x;
  if (e < NE){
    const int s = esrc[e], d = edst[e];
    ebd[atomicAdd(&curd[d],1)] = s;   // src list grouped by dst
    ebs[atomicAdd(&curm[s],1)] = d;   // dst list grouped by src
  }
}

// ---------------- driver ----------------
extern "C" void kernel_launch(void* const* d_in, const int* in_sizes, int n_in,
                              void* d_out, int out_size, void* d_ws, size_t ws_size,
                              hipStream_t stream)
{
  (void)in_sizes; (void)n_in; (void)out_size; (void)ws_size;
  const float* mirna_feat=(const float*)d_in[0];
  const float* dis_feat  =(const float*)d_in[1];
  const int*   m_id =(const int*)d_in[2];
  const int*   d_id =(const int*)d_in[3];
  const int*   esrc =(const int*)d_in[4];
  const int*   edst =(const int*)d_in[5];
  const float* Wm=(const float*)d_in[6];  const float* bm=(const float*)d_in[7];
  const float* Wd=(const float*)d_in[8];  const float* bd=(const float*)d_in[9];
  const float* m_emb=(const float*)d_in[10]; const float* d_emb=(const float*)d_in[11];
  const float* W1mdl=(const float*)d_in[12]; const float* b1md=(const float*)d_in[13];
  const float* W1mdr=(const float*)d_in[14];
  const float* W1dml=(const float*)d_in[15]; const float* b1dm=(const float*)d_in[16];
  const float* W1dmr=(const float*)d_in[17];
  const float* W2mdl=(const float*)d_in[18]; const float* b2md=(const float*)d_in[19];
  const float* W2mdr=(const float*)d_in[20];
  const float* W2dml=(const float*)d_in[21]; const float* b2dm=(const float*)d_in[22];
  const float* W2dmr=(const float*)d_in[23];

  size_t off = 0;
  char* base = (char*)d_ws;
  auto alloc = [&](size_t bytes)->void*{
    off = (off + 255) & ~(size_t)255;
    void* p = base + off; off += bytes; return p;
  };
  unsigned short* featm = (unsigned short*)alloc((size_t)NM*FIN*2);
  unsigned short* featd = (unsigned short*)alloc((size_t)ND*FIN*2);
  unsigned short* WmT   = (unsigned short*)alloc((size_t)H*FIN*2);
  unsigned short* WdT   = (unsigned short*)alloc((size_t)H*FIN*2);
  unsigned short* W1mdT = (unsigned short*)alloc((size_t)H1*1024*2);
  unsigned short* W1dmT = (unsigned short*)alloc((size_t)H1*1024*2);
  unsigned short* W2mdT = (unsigned short*)alloc((size_t)O*1024*2);
  unsigned short* W2dmT = (unsigned short*)alloc((size_t)O*1024*2);
  unsigned short* xm    = (unsigned short*)alloc((size_t)NM*H*2);
  unsigned short* xd    = (unsigned short*)alloc((size_t)ND*H*2);
  unsigned short* aggm  = (unsigned short*)alloc((size_t)NM*H*2);
  unsigned short* aggd  = (unsigned short*)alloc((size_t)ND*H*2);
  unsigned short* hm    = (unsigned short*)alloc((size_t)NM*H1*2);
  unsigned short* hd    = (unsigned short*)alloc((size_t)ND*H1*2);
  int* degd = (int*)alloc((size_t)(ND+NM)*4);
  int* degm = degd + ND;
  int* offd = (int*)alloc((size_t)(ND+1)*4);
  int* offm = (int*)alloc((size_t)(NM+1)*4);
  int* curd = (int*)alloc((size_t)ND*4);
  int* curm = (int*)alloc((size_t)NM*4);
  int* ebd  = (int*)alloc((size_t)NE*4);
  int* ebs  = (int*)alloc((size_t)NE*4);

  hipMemsetAsync(degd, 0, (size_t)(ND+NM)*4, stream);
  prep_all<<<PREPW_BLOCKS + CVT_BLOCKS + HIST_BLOCKS, 256, 0, stream>>>(
      Wm,Wd,W1mdl,W1mdr,W1dml,W1dmr,W2mdl,W2mdr,W2dml,W2dmr,
      WmT,WdT,W1mdT,W1dmT,W2mdT,W2dmT,
      mirna_feat, dis_feat, featm, featd,
      esrc, edst, degm, degd);
  scan_k<<<2,256,0,stream>>>(degd, offd, curd, degm, offm, curm);
  fill_k<<<(NE+255)/256,256,0,stream>>>(esrc, edst, curd, curm, ebd, ebs);

  // encoders: x = feat@W + b + emb[id]   (m-part + d-part in one grid)
  {
    GPart p0{featm, featm, WmT, bm, m_emb, m_id, xm, NM, 157};
    GPart p1{featd, featd, WdT, bd, d_emb, d_id, xd, ND, 63};
    gemm8w<0><<<dim3(220,4),512,0,stream>>>(p0, p1, FIN, FIN, H);
  }
  // layer-1 aggregation (both directions, one grid)
  agg2<<<(NM+ND)/4,256,0,stream>>>(xm, xd, offm, ebs, offd, ebd, aggm, aggd);
  // layer-1 SAGE: h = relu(agg@Wl + x@Wr + b)
  {
    GPart p0{aggm, xm, W1dmT, b1dm, nullptr, nullptr, hm, NM, 157};
    GPart p1{aggd, xd, W1mdT, b1md, nullptr, nullptr, hd, ND, 63};
    gemm8w<1><<<dim3(220,4),512,0,stream>>>(p0, p1, H, 1024, H1);
  }
  // layer-2 aggregation (reuse agg buffers)
  agg2<<<(NM+ND)/4,256,0,stream>>>(hm, hd, offm, ebs, offd, ebd, aggm, aggd);
  // layer-2 SAGE: o = agg@Wl + h@Wr + b  (fp32, straight to d_out; order: o_m then o_d)
  float* out_m = (float*)d_out;
  float* out_d = out_m + (size_t)NM*O;
  {
    GPart p0{aggm, hm, W2dmT, b2dm, nullptr, nullptr, out_m, NM, 157};
    GPart p1{aggd, hd, W2mdT, b2md, nullptr, nullptr, out_d, ND, 63};
    gemm8w<2><<<dim3(220,2),512,0,stream>>>(p0, p1, H1, 1024, O);
  }
}